// Round 3
// baseline (110.566 us; speedup 1.0000x reference)
//
#include <hip/hip_runtime.h>

constexpr int H  = 2048, W = 4096, HG = 16, WG = 32, BS = 128;
constexpr int S  = 2, Hs = H / S, Ws = W / S;
constexpr int TILE_R = 32, TILE_C = 64;     // tile in m-space (subsampled)
constexpr int LMAX = 1536;                  // max rects_m entries (2*Nc+Np)
constexpr int NB  = (Ws / TILE_C) * (Hs / TILE_R);   // 32*32 = 1024 blocks

// Single fused kernel:
//  Phase A: ticket-based match work (one box per ticket, 256 threads/box).
//           Deadlock-free: blocks loop grabbing tickets until exhausted, so any
//           resident block makes progress; results published via agent-release.
//  Phase B: spin (acquire) until all Nc boxes done, then grid_ig + mask raster.
__global__ __launch_bounds__(256) void k_fused(
    const float* __restrict__ bc, const float* __restrict__ bp,
    int Nc, int Np,
    int* __restrict__ ticket, int* __restrict__ done,
    int* __restrict__ wrect, float* __restrict__ val_c,
    int* __restrict__ bj_matched, int* __restrict__ rm, float* __restrict__ wm,
    float* __restrict__ out)
{
    __shared__ int4  Lr[LMAX];
    __shared__ float Lw[LMAX];
    __shared__ unsigned int bits[16];
    __shared__ int sh_t, cnt, glast, s_iso;
    __shared__ float red_f[4];
    __shared__ int   red_j[4];

    int tid  = threadIdx.x;
    int lane = tid & 63, wv = tid >> 6;

    // ---------------- Phase A: ticketed match ----------------
    for (;;) {
        __syncthreads();                         // protect sh_t / LDS reuse
        if (tid == 0) sh_t = atomicAdd(ticket, 1);
        __syncthreads();
        int i = sh_t;
        if (i >= Nc) break;

        float x1 = bc[i*5+0], y1 = bc[i*5+1], x2 = bc[i*5+2], y2 = bc[i*5+3], sc = bc[i*5+4];
        float ax1 = (float)(int)(x1*0.5f), ay1 = (float)(int)(y1*0.5f);
        float ax2 = (float)(int)(x2*0.5f), ay2 = (float)(int)(y2*0.5f);
        float areaA = (ax2-ax1)*(ay2-ay1);

        // IoU argmax over prev boxes (numpy first-max tie-break)
        float bi = -1.0f; int bj = 0;
        for (int j = tid; j < Np; j += 256) {
            float bx1 = (float)(int)(bp[j*5+0]*0.5f), by1 = (float)(int)(bp[j*5+1]*0.5f);
            float bx2 = (float)(int)(bp[j*5+2]*0.5f), by2 = (float)(int)(bp[j*5+3]*0.5f);
            float ix1 = fmaxf(ax1,bx1), iy1 = fmaxf(ay1,by1);
            float ix2 = fminf(ax2,bx2), iy2 = fminf(ay2,by2);
            float inter = fmaxf(ix2-ix1,0.0f)*fmaxf(iy2-iy1,0.0f);
            float areaB = (bx2-bx1)*(by2-by1);
            float iou = inter/(areaA+areaB-inter);
            if (iou > bi || (iou == bi && j < bj)) { bi = iou; bj = j; }
        }
        #pragma unroll
        for (int off = 32; off; off >>= 1) {
            float oi = __shfl_xor(bi, off);
            int   oj = __shfl_xor(bj, off);
            if (oi > bi || (oi == bi && oj < bj)) { bi = oi; bj = oj; }
        }
        if (tid == 0) s_iso = 0;
        if (lane == 0) { red_f[wv] = bi; red_j[wv] = bj; }
        __syncthreads();
        bi = red_f[0]; bj = red_j[0];
        #pragma unroll
        for (int w2 = 1; w2 < 4; w2++) {
            float oi = red_f[w2]; int oj = red_j[w2];
            if (oi > bi || (oi == bi && oj < bj)) { bi = oi; bj = oj; }
        }
        bool m = bi > 0.0f;

        int gx1=(int)x1/BS, gy1=(int)y1/BS, gx2=((int)x2-1)/BS, gy2=((int)y2-1)/BS;
        float pjx1=bp[bj*5+0], pjy1=bp[bj*5+1], pjx2=bp[bj*5+2], pjy2=bp[bj*5+3], spj=bp[bj*5+4];
        int hx1=(int)pjx1/BS, hy1=(int)pjy1/BS, hx2=((int)pjx2-1)/BS, hy2=((int)pjy2-1)/BS;

        // isolation vs all grid rects
        bool bad = false;
        int NT = Nc + Np;
        for (int k = tid; k < NT; k += 256) {
            const float* q = (k < Nc) ? &bc[(size_t)k*5] : &bp[(size_t)(k-Nc)*5];
            int qx1=(int)q[0]/BS, qy1=(int)q[1]/BS, qx2=((int)q[2]-1)/BS, qy2=((int)q[3]-1)/BS;
            bool ov = (gx1<=qx2)&&(qx1<=gx2)&&(gy1<=qy2)&&(qy1<=gy2);
            if (m) ov = ov || ((hx1<=qx2)&&(qx1<=hx2)&&(hy1<=qy2)&&(qy1<=hy2));
            bool excl = (k == i) || (m && k == Nc + bj);
            bad |= (ov && !excl);
        }
        if (__any(bad) && lane == 0) atomicOr(&s_iso, 1);
        __syncthreads();

        if (tid == 0) {
            bool big = ((int)y2 - (int)y1) >= 100;
            val_c[i] = (!s_iso && big && sc >= 0.7f) ? 2.0f : 1.0f;
            int4 wr = make_int4(gx1,gy1,gx2,gy2);
            if (m) { wr.x=min(gx1,hx1); wr.y=min(gy1,hy1); wr.z=max(gx2,hx2); wr.w=max(gy2,hy2); }
            ((int4*)wrect)[i] = wr;
            bj_matched[i] = m ? bj : -1;
            float ig = 1.0f - bi;
            ((int4*)rm)[i] = make_int4((int)(x1*0.5f),(int)(y1*0.5f),(int)(x2*0.5f),(int)(y2*0.5f));
            wm[i] = ig * sc;
            ((int4*)rm)[Nc+i] = make_int4((int)(pjx1*0.5f),(int)(pjy1*0.5f),(int)(pjx2*0.5f),(int)(pjy2*0.5f));
            wm[Nc+i] = m ? ig * spj : 0.0f;
            __threadfence();   // publish writes agent-wide
            __hip_atomic_fetch_add(done, 1, __ATOMIC_RELEASE, __HIP_MEMORY_SCOPE_AGENT);
        }
    }

    // ---------------- barrier: wait for all match work ----------------
    if (tid == 0) {
        while (__hip_atomic_load(done, __ATOMIC_ACQUIRE, __HIP_MEMORY_SCOPE_AGENT) < Nc)
            __builtin_amdgcn_s_sleep(4);
        cnt = 0; glast = -1;
    }
    if (tid < 16) bits[tid] = 0u;
    __syncthreads();

    // ---------------- Phase B: grid_ig + mask raster ----------------
    // matched_prev bitmap
    for (int i = tid; i < Nc; i += 256) {
        int bj = bj_matched[i];
        if (bj >= 0) atomicOr(&bits[bj >> 5], 1u << (bj & 31));
    }
    __syncthreads();

    int tileb = blockIdx.x;
    int bx = (tileb & 31) * TILE_C;
    int by = (tileb >> 5) * TILE_R;

    // cull curr-derived rows (precomputed in phase A)
    for (int r = tid; r < 2*Nc; r += 256) {
        int4 q = ((const int4*)rm)[r];
        float w = wm[r];
        if (w > 0.0f && q.x < bx+TILE_C && q.z > bx && q.y < by+TILE_R && q.w > by) {
            int idx = atomicAdd(&cnt, 1);
            Lr[idx] = q; Lw[idx] = w;
        }
    }
    // prev rows computed on the fly
    for (int j = tid; j < Np; j += 256) {
        bool mp = (bits[j >> 5] >> (j & 31)) & 1u;
        if (!mp) {
            float w = bp[j*5+4];
            if (w > 0.0f) {
                int4 q = make_int4((int)(bp[j*5+0]*0.5f),(int)(bp[j*5+1]*0.5f),
                                   (int)(bp[j*5+2]*0.5f),(int)(bp[j*5+3]*0.5f));
                if (q.x < bx+TILE_C && q.z > bx && q.y < by+TILE_R && q.w > by) {
                    int idx = atomicAdd(&cnt, 1);
                    Lr[idx] = q; Lw[idx] = w;
                }
            }
        }
    }

    // grid_ig: blocks 0..HG*WG-1 each own one cell
    int last = -1;
    if (tileb < HG*WG) {
        int gy = tileb / WG, gx = tileb % WG;
        int NT = Nc + Np;
        for (int r = tid; r < NT; r += 256) {
            int4 q; bool act;
            if (r < Nc) { q = ((const int4*)wrect)[r]; act = true; }
            else {
                int j = r - Nc;
                act = !((bits[j >> 5] >> (j & 31)) & 1u);
                q = make_int4((int)bp[j*5+0]/BS, (int)bp[j*5+1]/BS,
                              ((int)bp[j*5+2]-1)/BS, ((int)bp[j*5+3]-1)/BS);
            }
            if (act && gx >= q.x && gx <= q.z && gy >= q.y && gy <= q.w) last = r;
        }
        if (last >= 0) atomicMax(&glast, last);
    }
    __syncthreads();   // cnt + glast final

    if (tileb < HG*WG && tid == 0) {
        int g = glast;
        out[(size_t)H*W + tileb] = (g >= 0) ? (g < Nc ? val_c[g] : 1.0f) : 0.0f;
    }

    // per-pixel max over culled list, fused 2x2 upsample store
    int n = cnt;
    int tx = tid & 31;
    int ty = tid >> 5;
    int c0 = bx + tx * 2;
    int r0 = by + ty * 4;
    float mv[4][2];
    #pragma unroll
    for (int rr = 0; rr < 4; rr++) { mv[rr][0] = 0.0f; mv[rr][1] = 0.0f; }
    for (int k = 0; k < n; k++) {
        int4 q = Lr[k];          // broadcast LDS read
        float w = Lw[k];
        bool cx0 = (c0     >= q.x) && (c0     < q.z);
        bool cx1 = (c0 + 1 >= q.x) && (c0 + 1 < q.z);
        #pragma unroll
        for (int rr = 0; rr < 4; rr++) {
            int y = r0 + rr;
            bool cy = (y >= q.y) && (y < q.w);
            if (cy && cx0) mv[rr][0] = fmaxf(mv[rr][0], w);
            if (cy && cx1) mv[rr][1] = fmaxf(mv[rr][1], w);
        }
    }
    #pragma unroll
    for (int rr = 0; rr < 4; rr++) {
        int y = r0 + rr;
        float4 v = make_float4(mv[rr][0], mv[rr][0], mv[rr][1], mv[rr][1]);
        *(float4*)&out[(size_t)(2*y)     * W + 2*c0] = v;
        *(float4*)&out[(size_t)(2*y + 1) * W + 2*c0] = v;
    }
}

extern "C" void kernel_launch(void* const* d_in, const int* in_sizes, int n_in,
                              void* d_out, int out_size, void* d_ws, size_t ws_size,
                              hipStream_t stream)
{
    const float* bc = (const float*)d_in[0];
    const float* bp = (const float*)d_in[1];
    int Nc = in_sizes[0] / 5;
    int Np = in_sizes[1] / 5;
    float* out = (float*)d_out;

    // counters at ws[0..1]; data region starts at 64B offset
    int* ctr = (int*)d_ws;
    int* ticket = ctr + 0;
    int* done   = ctr + 1;
    int* w = (int*)((char*)d_ws + 64);
    int* wrect      = w;          w += Nc * 4;
    float* val_c    = (float*)w;  w += Nc;
    int* bj_matched = w;          w += Nc;
    int* rm         = w;          w += 2 * Nc * 4;
    float* wm       = (float*)w;  w += 2 * Nc;

    hipMemsetAsync(ctr, 0, 16, stream);
    k_fused<<<NB, 256, 0, stream>>>(bc, bp, Nc, Np, ticket, done,
                                    wrect, val_c, bj_matched, rm, wm, out);
}

// Round 4
// 96.021 us; speedup vs baseline: 1.1515x; 1.1515x over previous
//
#include <hip/hip_runtime.h>

constexpr int H  = 2048, W = 4096, HG = 16, WG = 32, BS = 128;
constexpr int S  = 2, Hs = H / S, Ws = W / S;
constexpr int TILE_R = 32, TILE_C = 64;     // tile in m-space (subsampled)
constexpr int LMAX = 1536;                  // max rects_m entries (2*Nc+Np)
constexpr int NB  = (Ws / TILE_C) * (Hs / TILE_R);   // 32*32 = 1024 blocks

// Single fused kernel, flag-based phase barrier:
//  Phase A: block b (< Nc) computes match for box b; publishes via ACQ_REL
//           sub-counter tree (8 lines) -> master -> release-store of flag.
//  All blocks spin on the (read-only) flag line, then run grid_ig + raster.
__global__ __launch_bounds__(256) void k_fused(
    const float* __restrict__ bc, const float* __restrict__ bp,
    int Nc, int Np,
    int* __restrict__ subc,      // 8 counters, stride 32 ints (128B lines)
    int* __restrict__ master,    // own line
    int* __restrict__ flag,      // own line
    int* __restrict__ wrect, float* __restrict__ val_c,
    int* __restrict__ bj_matched, int* __restrict__ rm, float* __restrict__ wm,
    float* __restrict__ out)
{
    __shared__ int4  Lr[LMAX];
    __shared__ float Lw[LMAX];
    __shared__ unsigned int bits[16];
    __shared__ int cnt, glast, s_iso;
    __shared__ float red_f[4];
    __shared__ int   red_j[4];

    int tid  = threadIdx.x;
    int lane = tid & 63, wv = tid >> 6;

    // ---------------- Phase A: one box per block ----------------
    int i = blockIdx.x;
    if (i < Nc) {
        float x1 = bc[i*5+0], y1 = bc[i*5+1], x2 = bc[i*5+2], y2 = bc[i*5+3], sc = bc[i*5+4];
        float ax1 = (float)(int)(x1*0.5f), ay1 = (float)(int)(y1*0.5f);
        float ax2 = (float)(int)(x2*0.5f), ay2 = (float)(int)(y2*0.5f);
        float areaA = (ax2-ax1)*(ay2-ay1);

        // IoU argmax over prev boxes (numpy first-max tie-break)
        float bi = -1.0f; int bj = 0;
        for (int j = tid; j < Np; j += 256) {
            float bx1 = (float)(int)(bp[j*5+0]*0.5f), by1 = (float)(int)(bp[j*5+1]*0.5f);
            float bx2 = (float)(int)(bp[j*5+2]*0.5f), by2 = (float)(int)(bp[j*5+3]*0.5f);
            float ix1 = fmaxf(ax1,bx1), iy1 = fmaxf(ay1,by1);
            float ix2 = fminf(ax2,bx2), iy2 = fminf(ay2,by2);
            float inter = fmaxf(ix2-ix1,0.0f)*fmaxf(iy2-iy1,0.0f);
            float areaB = (bx2-bx1)*(by2-by1);
            float iou = inter/(areaA+areaB-inter);
            if (iou > bi || (iou == bi && j < bj)) { bi = iou; bj = j; }
        }
        #pragma unroll
        for (int off = 32; off; off >>= 1) {
            float oi = __shfl_xor(bi, off);
            int   oj = __shfl_xor(bj, off);
            if (oi > bi || (oi == bi && oj < bj)) { bi = oi; bj = oj; }
        }
        if (tid == 0) s_iso = 0;
        if (lane == 0) { red_f[wv] = bi; red_j[wv] = bj; }
        __syncthreads();
        bi = red_f[0]; bj = red_j[0];
        #pragma unroll
        for (int w2 = 1; w2 < 4; w2++) {
            float oi = red_f[w2]; int oj = red_j[w2];
            if (oi > bi || (oi == bi && oj < bj)) { bi = oi; bj = oj; }
        }
        bool m = bi > 0.0f;

        int gx1=(int)x1/BS, gy1=(int)y1/BS, gx2=((int)x2-1)/BS, gy2=((int)y2-1)/BS;
        float pjx1=bp[bj*5+0], pjy1=bp[bj*5+1], pjx2=bp[bj*5+2], pjy2=bp[bj*5+3], spj=bp[bj*5+4];
        int hx1=(int)pjx1/BS, hy1=(int)pjy1/BS, hx2=((int)pjx2-1)/BS, hy2=((int)pjy2-1)/BS;

        // isolation vs all grid rects
        bool bad = false;
        int NT = Nc + Np;
        for (int k = tid; k < NT; k += 256) {
            const float* q = (k < Nc) ? &bc[(size_t)k*5] : &bp[(size_t)(k-Nc)*5];
            int qx1=(int)q[0]/BS, qy1=(int)q[1]/BS, qx2=((int)q[2]-1)/BS, qy2=((int)q[3]-1)/BS;
            bool ov = (gx1<=qx2)&&(qx1<=gx2)&&(gy1<=qy2)&&(qy1<=gy2);
            if (m) ov = ov || ((hx1<=qx2)&&(qx1<=hx2)&&(hy1<=qy2)&&(qy1<=hy2));
            bool excl = (k == i) || (m && k == Nc + bj);
            bad |= (ov && !excl);
        }
        if (__any(bad) && lane == 0) atomicOr(&s_iso, 1);
        __syncthreads();

        if (tid == 0) {
            bool big = ((int)y2 - (int)y1) >= 100;
            val_c[i] = (!s_iso && big && sc >= 0.7f) ? 2.0f : 1.0f;
            int4 wr = make_int4(gx1,gy1,gx2,gy2);
            if (m) { wr.x=min(gx1,hx1); wr.y=min(gy1,hy1); wr.z=max(gx2,hx2); wr.w=max(gy2,hy2); }
            ((int4*)wrect)[i] = wr;
            bj_matched[i] = m ? bj : -1;
            float ig = 1.0f - bi;
            ((int4*)rm)[i] = make_int4((int)(x1*0.5f),(int)(y1*0.5f),(int)(x2*0.5f),(int)(y2*0.5f));
            wm[i] = ig * sc;
            ((int4*)rm)[Nc+i] = make_int4((int)(pjx1*0.5f),(int)(pjy1*0.5f),(int)(pjx2*0.5f),(int)(pjy2*0.5f));
            wm[Nc+i] = m ? ig * spj : 0.0f;

            // completion tree: sub (ACQ_REL) -> master (ACQ_REL) -> flag (RELEASE)
            int s = i & 7;
            int subexp = (Nc + 7 - s) >> 3;             // #boxes with index%8==s
            int r = __hip_atomic_fetch_add(&subc[s*32], 1, __ATOMIC_ACQ_REL, __HIP_MEMORY_SCOPE_AGENT);
            if (r == subexp - 1) {
                int nsub = Nc < 8 ? Nc : 8;
                int r2 = __hip_atomic_fetch_add(master, 1, __ATOMIC_ACQ_REL, __HIP_MEMORY_SCOPE_AGENT);
                if (r2 == nsub - 1)
                    __hip_atomic_store(flag, 1, __ATOMIC_RELEASE, __HIP_MEMORY_SCOPE_AGENT);
            }
        }
    }

    // ---------------- barrier: read-only spin on flag line ----------------
    if (tid == 0) {
        while (__hip_atomic_load(flag, __ATOMIC_ACQUIRE, __HIP_MEMORY_SCOPE_AGENT) == 0)
            __builtin_amdgcn_s_sleep(8);
        cnt = 0; glast = -1;
    }
    if (tid < 16) bits[tid] = 0u;
    __syncthreads();

    // ---------------- Phase B: grid_ig + mask raster ----------------
    for (int b = tid; b < Nc; b += 256) {
        int bj = bj_matched[b];
        if (bj >= 0) atomicOr(&bits[bj >> 5], 1u << (bj & 31));
    }
    __syncthreads();

    int tileb = blockIdx.x;
    int bx = (tileb & 31) * TILE_C;
    int by = (tileb >> 5) * TILE_R;

    // cull curr-derived rows (precomputed in phase A)
    for (int r = tid; r < 2*Nc; r += 256) {
        int4 q = ((const int4*)rm)[r];
        float w = wm[r];
        if (w > 0.0f && q.x < bx+TILE_C && q.z > bx && q.y < by+TILE_R && q.w > by) {
            int idx = atomicAdd(&cnt, 1);
            Lr[idx] = q; Lw[idx] = w;
        }
    }
    // prev rows computed on the fly
    for (int j = tid; j < Np; j += 256) {
        bool mp = (bits[j >> 5] >> (j & 31)) & 1u;
        if (!mp) {
            float w = bp[j*5+4];
            if (w > 0.0f) {
                int4 q = make_int4((int)(bp[j*5+0]*0.5f),(int)(bp[j*5+1]*0.5f),
                                   (int)(bp[j*5+2]*0.5f),(int)(bp[j*5+3]*0.5f));
                if (q.x < bx+TILE_C && q.z > bx && q.y < by+TILE_R && q.w > by) {
                    int idx = atomicAdd(&cnt, 1);
                    Lr[idx] = q; Lw[idx] = w;
                }
            }
        }
    }

    // grid_ig: blocks 0..HG*WG-1 each own one cell
    int last = -1;
    if (tileb < HG*WG) {
        int gy = tileb / WG, gx = tileb % WG;
        int NT = Nc + Np;
        for (int r = tid; r < NT; r += 256) {
            int4 q; bool act;
            if (r < Nc) { q = ((const int4*)wrect)[r]; act = true; }
            else {
                int j = r - Nc;
                act = !((bits[j >> 5] >> (j & 31)) & 1u);
                q = make_int4((int)bp[j*5+0]/BS, (int)bp[j*5+1]/BS,
                              ((int)bp[j*5+2]-1)/BS, ((int)bp[j*5+3]-1)/BS);
            }
            if (act && gx >= q.x && gx <= q.z && gy >= q.y && gy <= q.w) last = r;
        }
        if (last >= 0) atomicMax(&glast, last);
    }
    __syncthreads();   // cnt + glast final

    if (tileb < HG*WG && tid == 0) {
        int g = glast;
        out[(size_t)H*W + tileb] = (g >= 0) ? (g < Nc ? val_c[g] : 1.0f) : 0.0f;
    }

    // per-pixel max over culled list, fused 2x2 upsample store
    int n = cnt;
    int tx = tid & 31;
    int ty = tid >> 5;
    int c0 = bx + tx * 2;
    int r0 = by + ty * 4;
    float mv[4][2];
    #pragma unroll
    for (int rr = 0; rr < 4; rr++) { mv[rr][0] = 0.0f; mv[rr][1] = 0.0f; }
    for (int k = 0; k < n; k++) {
        int4 q = Lr[k];          // broadcast LDS read
        float w = Lw[k];
        bool cx0 = (c0     >= q.x) && (c0     < q.z);
        bool cx1 = (c0 + 1 >= q.x) && (c0 + 1 < q.z);
        #pragma unroll
        for (int rr = 0; rr < 4; rr++) {
            int y = r0 + rr;
            bool cy = (y >= q.y) && (y < q.w);
            if (cy && cx0) mv[rr][0] = fmaxf(mv[rr][0], w);
            if (cy && cx1) mv[rr][1] = fmaxf(mv[rr][1], w);
        }
    }
    #pragma unroll
    for (int rr = 0; rr < 4; rr++) {
        int y = r0 + rr;
        float4 v = make_float4(mv[rr][0], mv[rr][0], mv[rr][1], mv[rr][1]);
        *(float4*)&out[(size_t)(2*y)     * W + 2*c0] = v;
        *(float4*)&out[(size_t)(2*y + 1) * W + 2*c0] = v;
    }
}

extern "C" void kernel_launch(void* const* d_in, const int* in_sizes, int n_in,
                              void* d_out, int out_size, void* d_ws, size_t ws_size,
                              hipStream_t stream)
{
    const float* bc = (const float*)d_in[0];
    const float* bp = (const float*)d_in[1];
    int Nc = in_sizes[0] / 5;
    int Np = in_sizes[1] / 5;
    float* out = (float*)d_out;

    // counter region: sub[8] at 128B stride (1024B) + master (line) + flag (line)
    int* ctr    = (int*)d_ws;
    int* subc   = ctr;                 // subc[s*32]
    int* master = ctr + 256;           // offset 1024B
    int* flag   = ctr + 288;           // offset 1152B
    int* w = (int*)((char*)d_ws + 2048);
    int* wrect      = w;          w += Nc * 4;
    float* val_c    = (float*)w;  w += Nc;
    int* bj_matched = w;          w += Nc;
    int* rm         = w;          w += 2 * Nc * 4;
    float* wm       = (float*)w;  w += 2 * Nc;

    hipMemsetAsync(ctr, 0, 2048, stream);
    k_fused<<<NB, 256, 0, stream>>>(bc, bp, Nc, Np, subc, master, flag,
                                    wrect, val_c, bj_matched, rm, wm, out);
}

// Round 5
// 30.728 us; speedup vs baseline: 3.5982x; 3.1248x over previous
//
#include <hip/hip_runtime.h>

constexpr int H  = 2048, W = 4096, HG = 16, WG = 32, BS = 128;
constexpr int S  = 2, Hs = H / S, Ws = W / S;
constexpr int TILE_R = 32, TILE_C = 64;     // tile in m-space (subsampled)
constexpr int LMAX = 1536;                  // max rects_m entries (2*Nc+Np)
constexpr int NB  = (Ws / TILE_C) * (Hs / TILE_R);   // 32*32 = 1024 blocks

#define AGT __HIP_MEMORY_SCOPE_AGENT
static __device__ __forceinline__ unsigned ld_u32(const unsigned* p) {
    return __hip_atomic_load(p, __ATOMIC_RELAXED, AGT);
}
static __device__ __forceinline__ unsigned long long ld_u64(const unsigned long long* p) {
    return __hip_atomic_load(p, __ATOMIC_RELAXED, AGT);
}
static __device__ __forceinline__ void st_u32(unsigned* p, unsigned v) {
    __hip_atomic_store(p, v, __ATOMIC_RELAXED, AGT);
}
static __device__ __forceinline__ void st_u64(unsigned long long* p, unsigned long long v) {
    __hip_atomic_store(p, v, __ATOMIC_RELAXED, AGT);
}
static __device__ __forceinline__ unsigned long long pack2(int a, int b) {
    return (unsigned long long)(unsigned)a | ((unsigned long long)(unsigned)b << 32);
}

// Single fused kernel. Cross-block traffic is 100% relaxed agent atomics
// (MALL-direct, sc1): no buffer_inv / buffer_wbl2 cache-maintenance storms.
//  Phase A: block i (< Nc) computes match for box i, publishes via relaxed
//           stores + s_waitcnt vmcnt(0) + relaxed counter tree -> flag.
//  All blocks spin (relaxed, s_sleep backoff) on flag, then grid_ig + raster.
__global__ __launch_bounds__(256) void k_fused(
    const float* __restrict__ bc, const float* __restrict__ bp,
    int Nc, int Np,
    unsigned* __restrict__ subc,      // 8 counters, stride 32 u32 (128B lines)
    unsigned* __restrict__ master,    // own line
    unsigned* __restrict__ flag,      // own line
    unsigned long long* __restrict__ wrect_u,   // [Nc*2] packed int4
    unsigned* __restrict__ val_c_u,             // [Nc] float bits
    unsigned* __restrict__ bj_u,                // [Nc] int bits (-1 = unmatched)
    unsigned long long* __restrict__ rm_u,      // [2Nc*2] packed int4
    unsigned* __restrict__ wm_u,                // [2Nc] float bits
    float* __restrict__ out)
{
    __shared__ int4  Lr[LMAX];
    __shared__ float Lw[LMAX];
    __shared__ unsigned bits[16];
    __shared__ int cnt, glast, s_iso;
    __shared__ float red_f[4];
    __shared__ int   red_j[4];

    int tid  = threadIdx.x;
    int lane = tid & 63, wv = tid >> 6;

    // ---------------- Phase A: one box per block ----------------
    int i = blockIdx.x;
    if (i < Nc) {
        float x1 = bc[i*5+0], y1 = bc[i*5+1], x2 = bc[i*5+2], y2 = bc[i*5+3], sc = bc[i*5+4];
        float ax1 = (float)(int)(x1*0.5f), ay1 = (float)(int)(y1*0.5f);
        float ax2 = (float)(int)(x2*0.5f), ay2 = (float)(int)(y2*0.5f);
        float areaA = (ax2-ax1)*(ay2-ay1);

        // IoU argmax over prev boxes (numpy first-max tie-break)
        float bi = -1.0f; int bj = 0;
        for (int j = tid; j < Np; j += 256) {
            float bx1 = (float)(int)(bp[j*5+0]*0.5f), by1 = (float)(int)(bp[j*5+1]*0.5f);
            float bx2 = (float)(int)(bp[j*5+2]*0.5f), by2 = (float)(int)(bp[j*5+3]*0.5f);
            float ix1 = fmaxf(ax1,bx1), iy1 = fmaxf(ay1,by1);
            float ix2 = fminf(ax2,bx2), iy2 = fminf(ay2,by2);
            float inter = fmaxf(ix2-ix1,0.0f)*fmaxf(iy2-iy1,0.0f);
            float areaB = (bx2-bx1)*(by2-by1);
            float iou = inter/(areaA+areaB-inter);
            if (iou > bi || (iou == bi && j < bj)) { bi = iou; bj = j; }
        }
        #pragma unroll
        for (int off = 32; off; off >>= 1) {
            float oi = __shfl_xor(bi, off);
            int   oj = __shfl_xor(bj, off);
            if (oi > bi || (oi == bi && oj < bj)) { bi = oi; bj = oj; }
        }
        if (tid == 0) s_iso = 0;
        if (lane == 0) { red_f[wv] = bi; red_j[wv] = bj; }
        __syncthreads();
        bi = red_f[0]; bj = red_j[0];
        #pragma unroll
        for (int w2 = 1; w2 < 4; w2++) {
            float oi = red_f[w2]; int oj = red_j[w2];
            if (oi > bi || (oi == bi && oj < bj)) { bi = oi; bj = oj; }
        }
        bool m = bi > 0.0f;

        int gx1=(int)x1/BS, gy1=(int)y1/BS, gx2=((int)x2-1)/BS, gy2=((int)y2-1)/BS;
        float pjx1=bp[bj*5+0], pjy1=bp[bj*5+1], pjx2=bp[bj*5+2], pjy2=bp[bj*5+3], spj=bp[bj*5+4];
        int hx1=(int)pjx1/BS, hy1=(int)pjy1/BS, hx2=((int)pjx2-1)/BS, hy2=((int)pjy2-1)/BS;

        // isolation vs all grid rects
        bool bad = false;
        int NT = Nc + Np;
        for (int k = tid; k < NT; k += 256) {
            const float* q = (k < Nc) ? &bc[(size_t)k*5] : &bp[(size_t)(k-Nc)*5];
            int qx1=(int)q[0]/BS, qy1=(int)q[1]/BS, qx2=((int)q[2]-1)/BS, qy2=((int)q[3]-1)/BS;
            bool ov = (gx1<=qx2)&&(qx1<=gx2)&&(gy1<=qy2)&&(qy1<=gy2);
            if (m) ov = ov || ((hx1<=qx2)&&(qx1<=hx2)&&(hy1<=qy2)&&(qy1<=hy2));
            bool excl = (k == i) || (m && k == Nc + bj);
            bad |= (ov && !excl);
        }
        if (__any(bad) && lane == 0) atomicOr(&s_iso, 1);
        __syncthreads();

        if (tid == 0) {
            bool big = ((int)y2 - (int)y1) >= 100;
            float vc = (!s_iso && big && sc >= 0.7f) ? 2.0f : 1.0f;
            int4 wr = make_int4(gx1,gy1,gx2,gy2);
            if (m) { wr.x=min(gx1,hx1); wr.y=min(gy1,hy1); wr.z=max(gx2,hx2); wr.w=max(gy2,hy2); }
            float ig = 1.0f - bi;
            // publish MALL-direct (relaxed agent atomics, no cache maintenance)
            st_u32(&val_c_u[i], __float_as_uint(vc));
            st_u64(&wrect_u[i*2+0], pack2(wr.x, wr.y));
            st_u64(&wrect_u[i*2+1], pack2(wr.z, wr.w));
            st_u32(&bj_u[i], (unsigned)(m ? bj : -1));
            st_u64(&rm_u[i*2+0], pack2((int)(x1*0.5f), (int)(y1*0.5f)));
            st_u64(&rm_u[i*2+1], pack2((int)(x2*0.5f), (int)(y2*0.5f)));
            st_u32(&wm_u[i], __float_as_uint(ig * sc));
            st_u64(&rm_u[(Nc+i)*2+0], pack2((int)(pjx1*0.5f), (int)(pjy1*0.5f)));
            st_u64(&rm_u[(Nc+i)*2+1], pack2((int)(pjx2*0.5f), (int)(pjy2*0.5f)));
            st_u32(&wm_u[Nc+i], __float_as_uint(m ? ig * spj : 0.0f));
            asm volatile("s_waitcnt vmcnt(0)" ::: "memory");   // data at MALL
            // relaxed counter tree; RMW-result dependency orders each level
            int s = i & 7;
            unsigned subexp = (unsigned)((Nc + 7 - s) >> 3);
            unsigned r = __hip_atomic_fetch_add(&subc[s*32], 1u, __ATOMIC_RELAXED, AGT);
            if (r == subexp - 1u) {
                unsigned nsub = (unsigned)(Nc < 8 ? Nc : 8);
                unsigned r2 = __hip_atomic_fetch_add(master, 1u, __ATOMIC_RELAXED, AGT);
                if (r2 == nsub - 1u)
                    st_u32(flag, 1u);
            }
        }
    }

    // ---------------- barrier: relaxed spin on flag (no cache ops) ----------------
    if (tid == 0) {
        while (ld_u32(flag) == 0u)
            __builtin_amdgcn_s_sleep(32);
        cnt = 0; glast = -1;
    }
    if (tid < 16) bits[tid] = 0u;
    __syncthreads();   // exec + compiler fence; all later reads are MALL-direct

    // ---------------- Phase B: grid_ig + mask raster ----------------
    for (int b = tid; b < Nc; b += 256) {
        unsigned bj = ld_u32(&bj_u[b]);
        if ((int)bj >= 0) atomicOr(&bits[bj >> 5], 1u << (bj & 31));
    }
    __syncthreads();

    int tileb = blockIdx.x;
    int bx = (tileb & 31) * TILE_C;
    int by = (tileb >> 5) * TILE_R;

    // cull curr-derived rows (published in phase A)
    for (int r = tid; r < 2*Nc; r += 256) {
        unsigned long long a = ld_u64(&rm_u[r*2+0]);
        unsigned long long b = ld_u64(&rm_u[r*2+1]);
        int4 q = make_int4((int)(unsigned)a, (int)(unsigned)(a >> 32),
                           (int)(unsigned)b, (int)(unsigned)(b >> 32));
        float w = __uint_as_float(ld_u32(&wm_u[r]));
        if (w > 0.0f && q.x < bx+TILE_C && q.z > bx && q.y < by+TILE_R && q.w > by) {
            int idx = atomicAdd(&cnt, 1);
            Lr[idx] = q; Lw[idx] = w;
        }
    }
    // prev rows computed on the fly from input boxes
    for (int j = tid; j < Np; j += 256) {
        bool mp = (bits[j >> 5] >> (j & 31)) & 1u;
        if (!mp) {
            float w = bp[j*5+4];
            if (w > 0.0f) {
                int4 q = make_int4((int)(bp[j*5+0]*0.5f),(int)(bp[j*5+1]*0.5f),
                                   (int)(bp[j*5+2]*0.5f),(int)(bp[j*5+3]*0.5f));
                if (q.x < bx+TILE_C && q.z > bx && q.y < by+TILE_R && q.w > by) {
                    int idx = atomicAdd(&cnt, 1);
                    Lr[idx] = q; Lw[idx] = w;
                }
            }
        }
    }

    // grid_ig: blocks 0..HG*WG-1 each own one cell
    int last = -1;
    if (tileb < HG*WG) {
        int gy = tileb / WG, gx = tileb % WG;
        int NT = Nc + Np;
        for (int r = tid; r < NT; r += 256) {
            int4 q; bool act;
            if (r < Nc) {
                unsigned long long a = ld_u64(&wrect_u[r*2+0]);
                unsigned long long b = ld_u64(&wrect_u[r*2+1]);
                q = make_int4((int)(unsigned)a, (int)(unsigned)(a >> 32),
                              (int)(unsigned)b, (int)(unsigned)(b >> 32));
                act = true;
            } else {
                int j = r - Nc;
                act = !((bits[j >> 5] >> (j & 31)) & 1u);
                q = make_int4((int)bp[j*5+0]/BS, (int)bp[j*5+1]/BS,
                              ((int)bp[j*5+2]-1)/BS, ((int)bp[j*5+3]-1)/BS);
            }
            if (act && gx >= q.x && gx <= q.z && gy >= q.y && gy <= q.w) last = r;
        }
        if (last >= 0) atomicMax(&glast, last);
    }
    __syncthreads();   // cnt + glast final

    if (tileb < HG*WG && tid == 0) {
        int g = glast;
        float gv = 0.0f;
        if (g >= 0) gv = (g < Nc) ? __uint_as_float(ld_u32(&val_c_u[g])) : 1.0f;
        out[(size_t)H*W + tileb] = gv;
    }

    // per-pixel max over culled list, fused 2x2 upsample store
    int n = cnt;
    int tx = tid & 31;
    int ty = tid >> 5;
    int c0 = bx + tx * 2;
    int r0 = by + ty * 4;
    float mv[4][2];
    #pragma unroll
    for (int rr = 0; rr < 4; rr++) { mv[rr][0] = 0.0f; mv[rr][1] = 0.0f; }
    for (int k = 0; k < n; k++) {
        int4 q = Lr[k];          // broadcast LDS read
        float w = Lw[k];
        bool cx0 = (c0     >= q.x) && (c0     < q.z);
        bool cx1 = (c0 + 1 >= q.x) && (c0 + 1 < q.z);
        #pragma unroll
        for (int rr = 0; rr < 4; rr++) {
            int y = r0 + rr;
            bool cy = (y >= q.y) && (y < q.w);
            if (cy && cx0) mv[rr][0] = fmaxf(mv[rr][0], w);
            if (cy && cx1) mv[rr][1] = fmaxf(mv[rr][1], w);
        }
    }
    #pragma unroll
    for (int rr = 0; rr < 4; rr++) {
        int y = r0 + rr;
        float4 v = make_float4(mv[rr][0], mv[rr][0], mv[rr][1], mv[rr][1]);
        *(float4*)&out[(size_t)(2*y)     * W + 2*c0] = v;
        *(float4*)&out[(size_t)(2*y + 1) * W + 2*c0] = v;
    }
}

extern "C" void kernel_launch(void* const* d_in, const int* in_sizes, int n_in,
                              void* d_out, int out_size, void* d_ws, size_t ws_size,
                              hipStream_t stream)
{
    const float* bc = (const float*)d_in[0];
    const float* bp = (const float*)d_in[1];
    int Nc = in_sizes[0] / 5;
    int Np = in_sizes[1] / 5;
    float* out = (float*)d_out;

    // counter region: sub[8] at 128B stride + master (1024B) + flag (1152B)
    unsigned* ctr    = (unsigned*)d_ws;
    unsigned* subc   = ctr;
    unsigned* master = ctr + 256;
    unsigned* flag   = ctr + 288;
    char* base = (char*)d_ws + 2048;
    unsigned long long* wrect_u = (unsigned long long*)base;            base += (size_t)Nc * 16;
    unsigned*           val_c_u = (unsigned*)base;                      base += (size_t)Nc * 4;
    unsigned*           bj_u    = (unsigned*)base;                      base += (size_t)Nc * 4;
    unsigned long long* rm_u    = (unsigned long long*)base;            base += (size_t)2 * Nc * 16;
    unsigned*           wm_u    = (unsigned*)base;                      base += (size_t)2 * Nc * 4;

    hipMemsetAsync(ctr, 0, 2048, stream);
    k_fused<<<NB, 256, 0, stream>>>(bc, bp, Nc, Np, subc, master, flag,
                                    wrect_u, val_c_u, bj_u, rm_u, wm_u, out);
}